// Round 3
// baseline (272.619 us; speedup 1.0000x reference)
//
#include <hip/hip_runtime.h>
#include <cstdint>
#include <cstddef>

#define B_N   16
#define G_N   128
#define FD_N  8192
#define KRED  4          // k-split count (4 chunks of 2048)
#define KCF   2048       // floats per k-chunk
#define RG_N  4          // row-groups of 32 q-rows

typedef unsigned short u16;
typedef u16  u16x8 __attribute__((ext_vector_type(8)));
typedef __bf16 bf16x8 __attribute__((ext_vector_type(8)));
typedef float f32x16 __attribute__((ext_vector_type(16)));

// ---- ws layout (float offsets). Everything written before read; NO zero-init needed.
#define QSUM_P   0        // [kch<4][b][row] (stride 2048 kept; only 4 slots used)
#define QSSQ_P   32768
#define KSUM_P   65536
#define KSSQ_P   98304
#define NSSQ_P   131072
#define SM_ROW   163840   // [b][row]
#define CE_ROW   165888
#define S_OFF    167936   // [b][128][128] fp32 normalized S
// u16 region: partials [b2=32][row 128][kch 4][col 128] bf16 = 4.2 MB (region unchanged)
#define PART_OFF_F 430080

__device__ __forceinline__ u16 f2bf(float f) {
    uint32_t u = __float_as_uint(f);
    u += 0x7FFFu + ((u >> 16) & 1u);      // RNE
    return (u16)(u >> 16);
}

// ================= K1: bf16 GEMM, block = (b, rowgroup, kchunk) ==============================
// grid = 16 * 4 * 4 = 256 blocks x 512 thr (1/CU). Output per block: 32 q-rows x 256 cols
// (128 k + 128 n), k-partial over a 2048-wide chunk.
// DRAM-order redesign: A (q) chunk staged to LDS as 32 rows x 8 KB CONTIGUOUS bursts
// (vs 256B visits before); B consumed register-direct, unroll-8 giving 256B in-time bursts.
// NO inter-stage barriers: one __syncthreads after the A stage, then free-running waves.
__global__ __launch_bounds__(512, 2)
void k_gemm(const float* __restrict__ q, const float* __restrict__ kM,
            const float* __restrict__ nM, float* __restrict__ ws)
{
    // A tile bf16 [32 rows][256 16B-units], unit index XOR-swizzled with (row&7)
    __shared__ __align__(16) u16 sA[32 * 2048];   // 128 KB

    const int tid = threadIdx.x;
    const int blk = blockIdx.x;       // b*16 + rg*4 + kch
    const int b   = blk >> 4;
    const int rg  = (blk >> 2) & 3;
    const int kch = blk & 3;

    // ---------------- A stage: q rows [rg*32, +32), cols [kch*2048, +2048) ----------------
    {
        const int r = tid >> 4;       // 0..31 local row
        const int c = tid & 15;       // 16 threads/row
        const float* Arow = q + (size_t)(b*G_N + rg*32 + r) * FD_N + kch*KCF;
        u16* aldrow = sA + r * 2048;  // row stride = 2048 u16 = 4 KB
        float ssA = 0.f, qqA = 0.f;
        #pragma unroll
        for (int j = 0; j < 16; ++j) {
            // logical unit U = j*16 + c  -> floats [U*8, U*8+8) = j*128 + c*8
            const float4 lo = *(const float4*)(Arow + j*128 + c*8);
            const float4 hi = *(const float4*)(Arow + j*128 + c*8 + 4);
            ssA += (lo.x + lo.y) + (lo.z + lo.w) + (hi.x + hi.y) + (hi.z + hi.w);
            qqA += lo.x*lo.x + lo.y*lo.y + lo.z*lo.z + lo.w*lo.w
                 + hi.x*hi.x + hi.y*hi.y + hi.z*hi.z + hi.w*hi.w;
            u16x8 h;
            h[0]=f2bf(lo.x); h[1]=f2bf(lo.y); h[2]=f2bf(lo.z); h[3]=f2bf(lo.w);
            h[4]=f2bf(hi.x); h[5]=f2bf(hi.y); h[6]=f2bf(hi.z); h[7]=f2bf(hi.w);
            *(u16x8*)(aldrow + (((j*16 + c) ^ (r & 7)) << 3)) = h;
        }
        // reduce over the 16 lanes of this row (lanes r*16..r*16+15 within wave)
        #pragma unroll
        for (int m = 8; m >= 1; m >>= 1) {
            ssA += __shfl_xor(ssA, m, 64);
            qqA += __shfl_xor(qqA, m, 64);
        }
        if (c == 0) {
            const int o = kch*2048 + b*G_N + rg*32 + r;
            ws[QSUM_P + o] = ssA; ws[QSSQ_P + o] = qqA;
        }
    }
    __syncthreads();

    // ---------------- main loop: wave-private B rows, register-direct ----------------
    const int lane  = tid & 63;
    const int wv    = tid >> 6;       // 8 waves
    const int ho    = wv >> 2;        // 0: B=k, 1: B=n
    const int bcol  = (wv & 3) * 32;  // 32-col group within the half
    const int lrow  = lane & 31;
    const int khalf = lane >> 5;

    const float* Brow = (ho ? nM : kM)
        + (size_t)(b*G_N + bcol + lrow) * FD_N + kch*KCF + khalf*8;
    const u16* afr = sA + lrow * 2048;

    f32x16 acc;
    #pragma unroll
    for (int e = 0; e < 16; ++e) acc[e] = 0.f;
    float ssB = 0.f, qqB = 0.f;

    #pragma unroll 8
    for (int kc = 0; kc < 128; ++kc) {
        const float4 lo = *(const float4*)(Brow + kc*16);
        const float4 hi = *(const float4*)(Brow + kc*16 + 4);
        ssB += (lo.x + lo.y) + (lo.z + lo.w) + (hi.x + hi.y) + (hi.z + hi.w);
        qqB += lo.x*lo.x + lo.y*lo.y + lo.z*lo.z + lo.w*lo.w
             + hi.x*hi.x + hi.y*hi.y + hi.z*hi.z + hi.w*hi.w;
        u16x8 hb;
        hb[0]=f2bf(lo.x); hb[1]=f2bf(lo.y); hb[2]=f2bf(lo.z); hb[3]=f2bf(lo.w);
        hb[4]=f2bf(hi.x); hb[5]=f2bf(hi.y); hb[6]=f2bf(hi.z); hb[7]=f2bf(hi.w);
        const bf16x8 bfv = __builtin_bit_cast(bf16x8, hb);
        const bf16x8 afv = __builtin_bit_cast(bf16x8,
            *(const u16x8*)(afr + ((((kc*2 + khalf) ^ (lrow & 7))) << 3)));
        acc = __builtin_amdgcn_mfma_f32_32x32x16_bf16(afv, bfv, acc, 0, 0, 0);
    }

    // ---- C partial write: [b2][row128][kch4][col128] bf16
    // C/D map: col(lane&31) = B-row, row(reg) = (reg&3)+8*(reg>>2)+4*khalf (A local row)
    {
        u16* pb = (u16*)(ws + PART_OFF_F) + (size_t)(b*2 + ho) * 65536;
        const int col = bcol + lrow;
        #pragma unroll
        for (int reg = 0; reg < 16; ++reg) {
            const int row = rg*32 + (reg & 3) + 8*(reg >> 2) + 4*khalf;
            pb[(row*4 + kch)*128 + col] = f2bf(acc[reg]);
        }
    }

    // ---- B row stats: lanes l and l+32 cover complementary 8-float slots of the row
    ssB += __shfl_xor(ssB, 32, 64);
    qqB += __shfl_xor(qqB, 32, 64);
    if (rg == 0 && khalf == 0) {   // B data identical across rg blocks: rg==0 owns stats
        const int o = kch*2048 + b*G_N + bcol + lrow;
        if (ho == 0) { ws[KSUM_P + o] = ssB; ws[KSSQ_P + o] = qqB; }
        else         { ws[NSSQ_P + o] = qqB; }
    }
}

// ================= K2: reduce chunks + normalize + write S / sm-row / CE-expsum-row ==========
// grid = 16b * 2half * 8rowgroups = 256 blocks x 256 thr. Also zeroes out[0] for K3's atomics.
// Partials [b2][row][kch4][col]: each row's 4 chunks are 1 KB contiguous.
__global__ __launch_bounds__(256)
void k_red2(float* __restrict__ ws, float* __restrict__ out)
{
    const int blk  = blockIdx.x;
    const int b    = blk >> 4;
    const int half = (blk >> 3) & 1;
    const int rg   = blk & 7;
    const int t    = threadIdx.x;
    const int lr   = t >> 4;            // 0..15
    const int i    = rg*16 + lr;
    const int c8   = t & 15;            // 8 cols each
    __shared__ float nrm[128];          // 1/||k_j|| or 1/||n_j||
    __shared__ float invq_s[16];

    if (blk == 0 && t == 0) out[0] = 0.f;

    if (t < 128) {
        float ss = 0.f;
        const float* p = ws + (half ? NSSQ_P : KSSQ_P) + b*G_N + t;
        #pragma unroll
        for (int kc2 = 0; kc2 < KRED; ++kc2) ss += p[kc2*2048];
        nrm[t] = 1.f / fmaxf(sqrtf(ss), 1e-12f);
    } else if (t < 144) {
        float ss = 0.f;
        const float* p = ws + QSSQ_P + b*G_N + rg*16 + (t - 128);
        #pragma unroll
        for (int kc2 = 0; kc2 < KRED; ++kc2) ss += p[kc2*2048];
        invq_s[t-128] = 1.f / fmaxf(sqrtf(ss), 1e-12f);
    }
    __syncthreads();

    const u16* part = (const u16*)(ws + PART_OFF_F) + (size_t)(b*2 + half) * 65536;
    float s[8] = {0,0,0,0,0,0,0,0};
    #pragma unroll
    for (int kc2 = 0; kc2 < KRED; ++kc2) {
        u16x8 h = *(const u16x8*)(part + (size_t)(i*4 + kc2)*128 + c8*8);
        #pragma unroll
        for (int e = 0; e < 8; ++e)
            s[e] += __uint_as_float(((uint32_t)h[e]) << 16);
    }
    const float iq = invq_s[lr];
    if (half == 0) {
        float smacc = 0.f;
        float S8[8];
        #pragma unroll
        for (int e = 0; e < 8; ++e) {
            int j = c8*8 + e;
            S8[e] = s[e] * iq * nrm[j];
            float d = S8[e] - (j == i ? 1.f : 0.f);
            smacc += d*d;
        }
        float* Sp = ws + S_OFF + (size_t)b*16384 + i*G_N + c8*8;
        float4 w0 = {S8[0],S8[1],S8[2],S8[3]};
        float4 w1 = {S8[4],S8[5],S8[6],S8[7]};
        *(float4*)Sp = w0; *(float4*)(Sp+4) = w1;
        #pragma unroll
        for (int m = 8; m >= 1; m >>= 1) smacc += __shfl_xor(smacc, m, 64);
        if (c8 == 0) ws[SM_ROW + b*G_N + i] = smacc;
    } else {
        float eacc = 0.f;
        #pragma unroll
        for (int e = 0; e < 8; ++e)
            eacc += __expf(5.f * s[e] * iq * nrm[c8*8+e]);
        #pragma unroll
        for (int m = 8; m >= 1; m >>= 1) eacc += __shfl_xor(eacc, m, 64);
        if (c8 == 0) ws[CE_ROW + b*G_N + i] = eacc;
    }
}

// ================= K3: tri/cyc/ce + weighted combine, atomic into out =================
// grid = 16b * 8rowgroups = 128 blocks x 256 thr. out[0] zeroed by K2 (stream-ordered).
__global__ __launch_bounds__(256)
void k_epi(float* __restrict__ ws, float* __restrict__ out)
{
    const int blk = blockIdx.x;
    const int b   = blk >> 3;
    const int i0  = (blk & 7) * 16;
    const int t   = threadIdx.x;
    __shared__ float sqv[128], skv[128], ddq[128], ddk[128];
    __shared__ float rbuf[4];
    const float c0 = (float)FD_N * 1e-6f * 1e-6f;

    const float* S = ws + S_OFF + (size_t)b * 16384;
    if (t < 128) {
        float qs=0, qq=0, ks=0, kq=0;
        #pragma unroll
        for (int kc2 = 0; kc2 < KRED; ++kc2) {
            int o = kc2*2048 + b*G_N + t;
            qs += ws[QSUM_P + o]; qq += ws[QSSQ_P + o];
            ks += ws[KSUM_P + o]; kq += ws[KSSQ_P + o];
        }
        float iq = 1.f/fmaxf(sqrtf(qq),1e-12f);
        float ik = 1.f/fmaxf(sqrtf(kq),1e-12f);
        float sq = qs*iq, sk = ks*ik;
        sqv[t]=sq; skv[t]=sk;
        float Stt = S[t*G_N + t];
        ddq[t] = sqrtf(fmaxf(2.f - 2.f*Stt + 2e-6f*(sq-sk) + c0, 0.f));
        ddk[t] = sqrtf(fmaxf(2.f - 2.f*Stt + 2e-6f*(sk-sq) + c0, 0.f));
    }
    __syncthreads();

    float tri=0.f, cyc=0.f, ce=0.f, sm=0.f;
    #pragma unroll
    for (int p = 0; p < 8; ++p) {
        int idx = p*256 + t;
        int i = i0 + (idx >> 7), j = idx & 127;
        if (i != j) {
            float S_ij = S[i*G_N + j];
            float dqk = sqrtf(fmaxf(2.f - 2.f*S_ij + 2e-6f*(sqv[i]-skv[j]) + c0, 0.f));
            tri += fmaxf(ddq[i] - dqk + 1.f, 0.f);
            float dkq = sqrtf(fmaxf(2.f - 2.f*S_ij + 2e-6f*(skv[j]-sqv[i]) + c0, 0.f));
            tri += fmaxf(ddk[j] - dkq + 1.f, 0.f);
            cyc += fabsf(S_ij - S[j*G_N + i]);
        }
    }
    if (t < 16) {
        int r = i0 + t;
        float lp = 5.f * S[r*G_N + r];
        ce = __logf(ws[CE_ROW + b*G_N + r] + __expf(lp)) - lp;
        sm = ws[SM_ROW + b*G_N + r];
    }
    float contrib = sm * (1.f/16384.f) + cyc * (1.f/16256.f) + ce * (1.f/16384.f)
                  + (float)(B_N - b) * tri * (1.f/32512.f);
    #pragma unroll
    for (int m = 32; m >= 1; m >>= 1) contrib += __shfl_xor(contrib, m, 64);
    if ((t & 63) == 0) rbuf[t >> 6] = contrib;
    __syncthreads();
    if (t == 0) atomicAdd(out, rbuf[0] + rbuf[1] + rbuf[2] + rbuf[3]);
}

extern "C" void kernel_launch(void* const* d_in, const int* in_sizes, int n_in,
                              void* d_out, int out_size, void* d_ws, size_t ws_size,
                              hipStream_t stream)
{
    const float* q  = (const float*)d_in[0];
    const float* kM = (const float*)d_in[1];
    const float* nM = (const float*)d_in[2];
    float* ws  = (float*)d_ws;
    float* out = (float*)d_out;

    k_gemm<<<B_N * RG_N * KRED, 512, 0, stream>>>(q, kM, nM, ws);
    k_red2<<<256, 256, 0, stream>>>(ws, out);
    k_epi<<<128, 256, 0, stream>>>(ws, out);
}

// Round 4
// 252.877 us; speedup vs baseline: 1.0781x; 1.0781x over previous
//
#include <hip/hip_runtime.h>
#include <cstdint>
#include <cstddef>

#define B_N   16
#define G_N   128
#define FD_N  8192
#define KCH_N 8          // k-split chunks in k_mm
#define KCB   1024       // bf16 elems per chunk (FD_N / KCH_N)
#define BKB   64         // bf16 elems per stage
#define NST   16         // KCB / BKB
#define NROWS 6144       // 3 matrices * 16b * 128 rows

typedef unsigned short u16;
typedef u16  u16x4 __attribute__((ext_vector_type(4)));
typedef u16  u16x8 __attribute__((ext_vector_type(8)));
typedef __bf16 bf16x8 __attribute__((ext_vector_type(8)));
typedef float f32x16 __attribute__((ext_vector_type(16)));

// ---- ws layout (float offsets). Everything written before read; NO zero-init needed.
// Stats are now FULL-ROW (single slot, written by k_prep).
#define QSUM_P   0        // [b*128 + row]
#define QSSQ_P   32768
#define KSUM_P   65536
#define KSSQ_P   98304
#define NSSQ_P   131072
#define SM_ROW   163840   // [b][row]
#define CE_ROW   165888
#define S_OFF    167936   // [b][128][128] fp32 normalized S
#define PART_OFF_F 430080 // u16 region: [256 blk][128][128] bf16 partials (8.4 MB)
#define BF16_OFF_F 2527232 // u16 region: [mat3][b16][row128][8192] bf16 inputs (96 MB)

__device__ __forceinline__ u16 f2bf(float f) {
    uint32_t u = __float_as_uint(f);
    u += 0x7FFFu + ((u >> 16) & 1u);      // RNE
    return (u16)(u >> 16);
}

__device__ __forceinline__ void load_lds16(const float* g, float* l) {
    __builtin_amdgcn_global_load_lds(
        (__attribute__((address_space(1))) void*)(g),
        (__attribute__((address_space(3))) void*)(l),
        16, 0, 0);
}

#define WAITV4() asm volatile("s_waitcnt vmcnt(4)" ::: "memory")
#define WAITV0() asm volatile("s_waitcnt vmcnt(0)" ::: "memory")

// ================= K0: streaming convert fp32->bf16 + full-row stats =========================
// grid = 1536 x 256 (4 waves/block, ONE WAVE PER 32-KB ROW, fully sequential slabs).
// This is exactly the m13 dense-stream pattern: read 192 MB once, write 96 MB bf16 to ws.
// The bf16 copy lands in L3 (96 MB < 256 MB) so k_mm's reads are L3-hits.
__global__ __launch_bounds__(256)
void k_prep(const float* __restrict__ q, const float* __restrict__ kM,
            const float* __restrict__ nM, float* __restrict__ ws)
{
    const int lane = threadIdx.x & 63;
    const int wv   = threadIdx.x >> 6;
    const int R    = blockIdx.x * 4 + wv;       // global row 0..6143
    const int mat  = R >> 11;                    // 0=q 1=k 2=n
    const int r    = R & 2047;                   // b*128 + row

    const float* src = (mat == 0 ? q : (mat == 1 ? kM : nM)) + (size_t)r * FD_N;
    u16* dst = (u16*)(ws + BF16_OFF_F) + (size_t)R * FD_N;

    float ss = 0.f, qq = 0.f;
    #pragma unroll 8
    for (int j = 0; j < 32; ++j) {
        const float4 v = *(const float4*)(src + (size_t)(j*64 + lane)*4);
        ss += (v.x + v.y) + (v.z + v.w);
        qq += v.x*v.x + v.y*v.y + v.z*v.z + v.w*v.w;
        u16x4 h;
        h[0]=f2bf(v.x); h[1]=f2bf(v.y); h[2]=f2bf(v.z); h[3]=f2bf(v.w);
        *(u16x4*)(dst + (size_t)(j*64 + lane)*4) = h;
    }
    #pragma unroll
    for (int m = 32; m >= 1; m >>= 1) {
        ss += __shfl_xor(ss, m, 64);
        qq += __shfl_xor(qq, m, 64);
    }
    if (lane == 0) {
        if (mat == 0)      { ws[QSUM_P + r] = ss; ws[QSSQ_P + r] = qq; }
        else if (mat == 1) { ws[KSUM_P + r] = ss; ws[KSSQ_P + r] = qq; }
        else               { ws[NSSQ_P + r] = qq; }
    }
}

// ================= K1: bf16 GEMM 128x128 tile on the L3-resident bf16 copy ===================
// grid = 16b * 2half * 8kch = 256 blocks x 512 thr (1/CU). R1-proven pipeline:
// global_load_lds width-16, double-buffered, counted vmcnt(4) (other buffer's 4 loads stay in
// flight across both barriers). Source carries the inverse XOR-swizzle (16B unit ^ (row&7));
// LDS linear; ds_read applies the same XOR (residual 4-way conflict). No conversion, no stats.
__global__ __launch_bounds__(512, 2)
void k_mm(float* __restrict__ ws)
{
    __shared__ __align__(16) u16 sA[2][G_N * BKB];   // 2 x 16 KB
    __shared__ __align__(16) u16 sB[2][G_N * BKB];   // 2 x 16 KB  (64 KB total)

    const int tid = threadIdx.x;
    const int blk = blockIdx.x;       // b*16 + half*8 + kch
    const int b    = blk >> 4;
    const int rem  = blk & 15;
    const int half = rem >> 3;
    const int kch  = rem & 7;

    const int lane  = tid & 63;
    const int wv    = tid >> 6;       // 8 waves
    const int wm    = wv >> 2;        // 0..1 -> 64-row block
    const int wn    = wv & 3;         // 0..3 -> 32-col block
    const int khalf = lane >> 5;
    const int lrow  = lane & 31;
    const int rA0 = wm*64 + lrow;
    const int rB0 = wn*32 + lrow;

    const u16* bf = (const u16*)(ws + BF16_OFF_F);
    const u16* Abase = bf + (size_t)(b*G_N) * FD_N + kch*KCB;
    const u16* Bbase = bf + (size_t)(((half ? 2 : 1)*2048) + b*G_N) * FD_N + kch*KCB;

    // staging: wave wv covers rows [wv*16, wv*16+16), 8 rows per instruction.
    // lane -> row = base + lane>>3, 16B-unit s = lane&7; source unit = s ^ (row&7).
    const int srow = wv*16 + (lane >> 3);
    const size_t gsw = (size_t)srow * FD_N + (size_t)(((lane & 7) ^ (srow & 7)) << 3);
    const int l0 = wv * 1024;         // u16 offset of wave's first 8-row chunk (wave-uniform)
    const int l1 = l0 + 512;

#define STAGE(ST, T) do {                                                     \
        const size_t tof_ = gsw + (size_t)((T) * BKB);                        \
        load_lds16((const float*)(Abase + tof_),            (float*)(&sA[ST][l0])); \
        load_lds16((const float*)(Bbase + tof_),            (float*)(&sB[ST][l0])); \
        load_lds16((const float*)(Abase + tof_ + 8*FD_N),   (float*)(&sA[ST][l1])); \
        load_lds16((const float*)(Bbase + tof_ + 8*FD_N),   (float*)(&sB[ST][l1])); \
    } while (0)

#define FRAG(SP, R, KC)                                                       \
    __builtin_bit_cast(bf16x8, *(const u16x8*)((SP) + (R)*BKB +               \
        ((((KC)*2 + khalf) ^ ((R)&7)) << 3)))

#define COMPUTE(ST) do {                                                      \
        const u16* dA_ = &sA[ST][0];                                          \
        const u16* dB_ = &sB[ST][0];                                          \
        __builtin_amdgcn_s_setprio(1);                                        \
        _Pragma("unroll")                                                     \
        for (int kc = 0; kc < 4; ++kc) {                                      \
            bf16x8 a0_ = FRAG(dA_, rA0,      kc);                             \
            bf16x8 a1_ = FRAG(dA_, rA0 + 32, kc);                             \
            bf16x8 b0_ = FRAG(dB_, rB0,      kc);                             \
            acc[0] = __builtin_amdgcn_mfma_f32_32x32x16_bf16(a0_, b0_, acc[0], 0,0,0); \
            acc[1] = __builtin_amdgcn_mfma_f32_32x32x16_bf16(a1_, b0_, acc[1], 0,0,0); \
        }                                                                     \
        __builtin_amdgcn_s_setprio(0);                                        \
    } while (0)

    f32x16 acc[2];
    #pragma unroll
    for (int mb = 0; mb < 2; ++mb)
      #pragma unroll
      for (int e = 0; e < 16; ++e) acc[mb][e] = 0.f;

    // prologue: both buffers in flight (8 outstanding DMA loads per wave)
    STAGE(0, 0);
    STAGE(1, 1);

    for (int t = 0; t < NST - 2; t += 2) {
        WAITV4();
        __builtin_amdgcn_s_barrier();
        COMPUTE(0);
        __builtin_amdgcn_s_barrier();
        STAGE(0, t + 2);

        WAITV4();
        __builtin_amdgcn_s_barrier();
        COMPUTE(1);
        __builtin_amdgcn_s_barrier();
        STAGE(1, t + 3);
    }
    // stage NST-2
    WAITV4();
    __builtin_amdgcn_s_barrier();
    COMPUTE(0);
    __builtin_amdgcn_s_barrier();
    // stage NST-1 (last: drain)
    WAITV0();
    __builtin_amdgcn_s_barrier();
    COMPUTE(1);

    // bf16 partial C: C/D layout col=lane&31, row=(reg&3)+8*(reg>>2)+4*(lane>>5)
    u16* part = (u16*)(ws + PART_OFF_F) + ((size_t)blk << 14);
    #pragma unroll
    for (int mb = 0; mb < 2; ++mb) {
        const int col = wn*32 + lrow;
        const int rbase = wm*64 + mb*32 + 4*khalf;
        #pragma unroll
        for (int reg = 0; reg < 16; ++reg) {
            const int row = rbase + (reg & 3) + 8*(reg >> 2);
            part[row*G_N + col] = f2bf(acc[mb][reg]);
        }
    }
#undef STAGE
#undef FRAG
#undef COMPUTE
}

// ================= K2: reduce 8 chunks + normalize + write S / sm-row / CE-expsum-row ========
// grid = 16b * 2half * 8rowgroups = 256 blocks x 256 thr. Also zeroes out[0] for K3's atomics.
__global__ __launch_bounds__(256)
void k_red2(float* __restrict__ ws, float* __restrict__ out)
{
    const int blk  = blockIdx.x;
    const int b    = blk >> 4;
    const int half = (blk >> 3) & 1;
    const int rg   = blk & 7;
    const int t    = threadIdx.x;
    const int lr   = t >> 4;            // 0..15
    const int i    = rg*16 + lr;
    const int c8   = t & 15;            // 8 cols each
    __shared__ float nrm[128];          // 1/||k_j|| or 1/||n_j||
    __shared__ float invq_s[16];

    if (blk == 0 && t == 0) out[0] = 0.f;

    if (t < 128) {
        const float ss = ws[(half ? NSSQ_P : KSSQ_P) + b*G_N + t];
        nrm[t] = 1.f / fmaxf(sqrtf(ss), 1e-12f);
    } else if (t < 144) {
        const float ss = ws[QSSQ_P + b*G_N + rg*16 + (t - 128)];
        invq_s[t-128] = 1.f / fmaxf(sqrtf(ss), 1e-12f);
    }
    __syncthreads();

    const u16* part = (const u16*)(ws + PART_OFF_F);
    float s[8] = {0,0,0,0,0,0,0,0};
    #pragma unroll
    for (int kc2 = 0; kc2 < KCH_N; ++kc2) {
        const size_t idx = ((size_t)(b*16 + half*8 + kc2) << 14) + i*G_N + c8*8;
        u16x8 h = *(const u16x8*)(part + idx);
        #pragma unroll
        for (int e = 0; e < 8; ++e)
            s[e] += __uint_as_float(((uint32_t)h[e]) << 16);
    }
    const float iq = invq_s[lr];
    if (half == 0) {
        float smacc = 0.f;
        float S8[8];
        #pragma unroll
        for (int e = 0; e < 8; ++e) {
            int j = c8*8 + e;
            S8[e] = s[e] * iq * nrm[j];
            float d = S8[e] - (j == i ? 1.f : 0.f);
            smacc += d*d;
        }
        float* Sp = ws + S_OFF + (size_t)b*16384 + i*G_N + c8*8;
        float4 w0 = {S8[0],S8[1],S8[2],S8[3]};
        float4 w1 = {S8[4],S8[5],S8[6],S8[7]};
        *(float4*)Sp = w0; *(float4*)(Sp+4) = w1;
        #pragma unroll
        for (int m = 8; m >= 1; m >>= 1) smacc += __shfl_xor(smacc, m, 64);
        if (c8 == 0) ws[SM_ROW + b*G_N + i] = smacc;
    } else {
        float eacc = 0.f;
        #pragma unroll
        for (int e = 0; e < 8; ++e)
            eacc += __expf(5.f * s[e] * iq * nrm[c8*8+e]);
        #pragma unroll
        for (int m = 8; m >= 1; m >>= 1) eacc += __shfl_xor(eacc, m, 64);
        if (c8 == 0) ws[CE_ROW + b*G_N + i] = eacc;
    }
}

// ================= K3: tri/cyc/ce + weighted combine, atomic into out =================
// grid = 16b * 8rowgroups = 128 blocks x 256 thr. out[0] zeroed by K2 (stream-ordered).
__global__ __launch_bounds__(256)
void k_epi(float* __restrict__ ws, float* __restrict__ out)
{
    const int blk = blockIdx.x;
    const int b   = blk >> 3;
    const int i0  = (blk & 7) * 16;
    const int t   = threadIdx.x;
    __shared__ float sqv[128], skv[128], ddq[128], ddk[128];
    __shared__ float rbuf[4];
    const float c0 = (float)FD_N * 1e-6f * 1e-6f;

    const float* S = ws + S_OFF + (size_t)b * 16384;
    if (t < 128) {
        const float qs = ws[QSUM_P + b*G_N + t];
        const float qq = ws[QSSQ_P + b*G_N + t];
        const float ks = ws[KSUM_P + b*G_N + t];
        const float kq = ws[KSSQ_P + b*G_N + t];
        float iq = 1.f/fmaxf(sqrtf(qq),1e-12f);
        float ik = 1.f/fmaxf(sqrtf(kq),1e-12f);
        float sq = qs*iq, sk = ks*ik;
        sqv[t]=sq; skv[t]=sk;
        float Stt = S[t*G_N + t];
        ddq[t] = sqrtf(fmaxf(2.f - 2.f*Stt + 2e-6f*(sq-sk) + c0, 0.f));
        ddk[t] = sqrtf(fmaxf(2.f - 2.f*Stt + 2e-6f*(sk-sq) + c0, 0.f));
    }
    __syncthreads();

    float tri=0.f, cyc=0.f, ce=0.f, sm=0.f;
    #pragma unroll
    for (int p = 0; p < 8; ++p) {
        int idx = p*256 + t;
        int i = i0 + (idx >> 7), j = idx & 127;
        if (i != j) {
            float S_ij = S[i*G_N + j];
            float dqk = sqrtf(fmaxf(2.f - 2.f*S_ij + 2e-6f*(sqv[i]-skv[j]) + c0, 0.f));
            tri += fmaxf(ddq[i] - dqk + 1.f, 0.f);
            float dkq = sqrtf(fmaxf(2.f - 2.f*S_ij + 2e-6f*(skv[j]-sqv[i]) + c0, 0.f));
            tri += fmaxf(ddk[j] - dkq + 1.f, 0.f);
            cyc += fabsf(S_ij - S[j*G_N + i]);
        }
    }
    if (t < 16) {
        int r = i0 + t;
        float lp = 5.f * S[r*G_N + r];
        ce = __logf(ws[CE_ROW + b*G_N + r] + __expf(lp)) - lp;
        sm = ws[SM_ROW + b*G_N + r];
    }
    float contrib = sm * (1.f/16384.f) + cyc * (1.f/16256.f) + ce * (1.f/16384.f)
                  + (float)(B_N - b) * tri * (1.f/32512.f);
    #pragma unroll
    for (int m = 32; m >= 1; m >>= 1) contrib += __shfl_xor(contrib, m, 64);
    if ((t & 63) == 0) rbuf[t >> 6] = contrib;
    __syncthreads();
    if (t == 0) atomicAdd(out, rbuf[0] + rbuf[1] + rbuf[2] + rbuf[3]);
}

extern "C" void kernel_launch(void* const* d_in, const int* in_sizes, int n_in,
                              void* d_out, int out_size, void* d_ws, size_t ws_size,
                              hipStream_t stream)
{
    const float* q  = (const float*)d_in[0];
    const float* kM = (const float*)d_in[1];
    const float* nM = (const float*)d_in[2];
    float* ws  = (float*)d_ws;
    float* out = (float*)d_out;

    k_prep<<<NROWS/4, 256, 0, stream>>>(q, kM, nM, ws);
    k_mm<<<256, 512, 0, stream>>>(ws);
    k_red2<<<256, 256, 0, stream>>>(ws, out);
    k_epi<<<128, 256, 0, stream>>>(ws, out);
}